// Round 13
// baseline (2142.098 us; speedup 1.0000x reference)
//
#include <hip/hip_runtime.h>

// Problem constants (from reference)
constexpr int Bb = 128;    // batch
constexpr int Nn = 50000;  // nodes
constexpr int Ll = 8;      // layers
constexpr int Ee = 250000; // edges per layer
constexpr int Uu = 10000;  // unique dst per layer
constexpr int Gg = 20000;  // genes
constexpr int Rr = 2000;   // roots
constexpr int Cc = 2;      // classes

// Binning parameters
constexpr int NB1 = 40;    // buckets (dst >> 8), 256 dsts each
constexpr int BW1 = 256;   // dsts per bucket
constexpr int CAP = 7424;  // region entries per (layer,bucket); mean 6400, sd ~79
constexpr int CH2 = 256;   // partition blocks per layer
constexpr int RIT = Uu * 32;   // reduce work items per layer
constexpr int NCHK = RIT / 256;  // 1250 chunks per layer
constexpr int NSTG = 7;    // fp8 staging slots (layer 7's outputs never re-read)
constexpr int GRID = 1024; // persistent kernel: 4 blocks/CU x 256 CU, co-resident

typedef __attribute__((ext_vector_type(2))) float f32x2;

// h_t (bf16, node rows, 256B/row): genes + direct node-row writes each layer;
//   read only by head (barrier ordering = .at[].set ordering).
// h8 (fp8 e4m3, 128B/row): node rows + append-only log slots (layer li outputs
//   at rows Nn+li*Uu..); the ONLY gather source. rowof[li][n] (baked into ssrc
//   by emit) points gathers at the pre-layer-li row -> no scatter copies.
// fused_layers: all 8 layers + head in ONE dispatch; software grid barriers.

__device__ __forceinline__ float b2f(unsigned short x) {
    return __uint_as_float((unsigned)x << 16);
}
__device__ __forceinline__ unsigned short f2b(float f) {  // RTNE
    unsigned u = __float_as_uint(f);
    return (unsigned short)((u + 0x7FFFu + ((u >> 16) & 1u)) >> 16);
}
__device__ __forceinline__ unsigned pkbf(float a, float b) {
    return (unsigned)f2b(a) | ((unsigned)f2b(b) << 16);
}

__global__ void zero_kernel(unsigned int* __restrict__ hz, unsigned int* __restrict__ h8z,
                            unsigned int* __restrict__ pz, int* __restrict__ gcur,
                            int* __restrict__ bar, int* __restrict__ work) {
    int idx = blockIdx.x * blockDim.x + threadIdx.x;
    if (idx < Nn * 64) hz[idx] = 0u;                 // h_t node rows (bf16)
    if (idx < Nn * 32) h8z[idx] = 0u;                // h8 node rows (fp8 0x00 == 0.0)
    if (idx < Ll * Nn / 2) pz[idx] = 0xFFFFFFFFu;    // postab init (0xFFFF per u16)
    if (idx < Ll * NB1) gcur[idx] = 0;
    if (idx < Ll) { bar[idx] = 0; work[idx] = 0; }   // persistent-kernel state
}

// gene scatter (LDS tile transpose) into BOTH mirrors + postab fill.
__global__ __launch_bounds__(256) void genes_kernel(const float* __restrict__ X,
                                                    const int* __restrict__ gmap,
                                                    const int* __restrict__ dstu,
                                                    unsigned short* __restrict__ h,
                                                    unsigned int* __restrict__ h8,
                                                    unsigned short* __restrict__ postab) {
    int gt = blockIdx.x * 256 + (int)threadIdx.x;
    if (gt < Ll * Uu) {
        int li = gt / Uu;
        postab[(size_t)li * Nn + dstu[gt]] = (unsigned short)(gt - li * Uu);
    }
    int g0 = blockIdx.x * 32;
    __shared__ float tile[32][129];
    #pragma unroll
    for (int i = 0; i < 16; ++i) {
        int idx = i * 256 + (int)threadIdx.x;
        int gl = idx & 31, b = idx >> 5;          // b in 0..127
        tile[gl][b] = X[(size_t)b * Gg + g0 + gl];
    }
    __syncthreads();
    #pragma unroll
    for (int i = 0; i < 16; ++i) {
        int idx = i * 256 + (int)threadIdx.x;
        int b = idx & 127, gl = idx >> 7;         // gl in 0..31
        h[(size_t)gmap[g0 + gl] * Bb + b] = f2b(tile[gl][b]);
    }
    #pragma unroll
    for (int i = 0; i < 4; ++i) {
        int idx = i * 256 + (int)threadIdx.x;     // 0..1023
        int q = idx & 31, gl = idx >> 5;          // q = b-quad, gl in 0..31
        int node = gmap[g0 + gl];
        int w8 = __builtin_amdgcn_cvt_pk_fp8_f32(tile[gl][q * 4 + 0], tile[gl][q * 4 + 1], 0, false);
        w8 = __builtin_amdgcn_cvt_pk_fp8_f32(tile[gl][q * 4 + 2], tile[gl][q * 4 + 3], w8, true);
        h8[(size_t)node * 32 + q] = (unsigned int)w8;
    }
}

// rowof[li][n]: row of n's latest value before layer li.
__global__ void rowof_kernel(const unsigned short* __restrict__ postab,
                             unsigned int* __restrict__ rowof) {
    int n = blockIdx.x * 256 + (int)threadIdx.x;
    if (n >= Nn) return;
    unsigned r = (unsigned)n;
    rowof[n] = r;                                 // level 0: identity
    #pragma unroll
    for (int li = 1; li < Ll; ++li) {
        unsigned short p = postab[(size_t)(li - 1) * Nn + n];
        if (p != 0xFFFFu) r = (unsigned)(Nn + (li - 1) * Uu + (int)p);
        rowof[(size_t)li * Nn + n] = r;
    }
}

// Two-pass direct scatter partition (unchanged).
__global__ __launch_bounds__(256) void part_kernel(const int* __restrict__ src,
                                                   const int* __restrict__ dstp,
                                                   int* __restrict__ gcur,
                                                   unsigned int* __restrict__ region) {
    int li = blockIdx.x / CH2, ch = blockIdx.x % CH2;
    const int ePer = (Ee + CH2 - 1) / CH2;        // 977
    int e0 = ch * ePer, e1 = min(e0 + ePer, Ee);
    const int* s = src + (size_t)li * Ee;
    const int* d = dstp + (size_t)li * Ee;

    __shared__ int hist[NB1];
    __shared__ int base[NB1];
    __shared__ int cur[NB1];
    if (threadIdx.x < NB1) { hist[threadIdx.x] = 0; cur[threadIdx.x] = 0; }
    __syncthreads();

    for (int e = e0 + (int)threadIdx.x; e < e1; e += 256)
        atomicAdd(&hist[d[e] >> 8], 1);
    __syncthreads();

    if (threadIdx.x < NB1) {
        int c = hist[threadIdx.x];
        base[threadIdx.x] = (c > 0) ? atomicAdd(&gcur[li * NB1 + (int)threadIdx.x], c) : 0;
    }
    __syncthreads();

    for (int e = e0 + (int)threadIdx.x; e < e1; e += 256) {
        int dd = d[e];
        int bkt = dd >> 8;
        unsigned int packed = ((unsigned int)s[e] << 8) | (unsigned int)(dd & 255);
        int pos = base[bkt] + atomicAdd(&cur[bkt], 1);
        region[((size_t)li * NB1 + bkt) * CAP + pos] = packed;
    }
}

// Per-bucket counting sort (256 bins) in LDS; writes rp + rowof-remapped ssrc.
__global__ __launch_bounds__(256) void emit_kernel(const unsigned int* __restrict__ region,
                                                   const int* __restrict__ gcur,
                                                   const unsigned int* __restrict__ rowof,
                                                   unsigned int* __restrict__ ssrc,
                                                   int* __restrict__ rp) {
    int li = blockIdx.x / NB1, b = blockIdx.x % NB1;
    int n = gcur[li * NB1 + b];
    const unsigned int* r = region + ((size_t)li * NB1 + b) * CAP;
    __shared__ int hh[BW1];
    __shared__ int ofs[BW1];
    __shared__ int sbase;
    __shared__ unsigned short lout[CAP];
    if (threadIdx.x < BW1) hh[threadIdx.x] = 0;
    // wave 0: inline exclusive prefix over the 40 bucket totals -> this bucket's base
    if (threadIdx.x < 64) {
        int t = threadIdx.x;
        int v = (t < NB1) ? gcur[li * NB1 + t] : 0;
        int sc = v;
        #pragma unroll
        for (int off = 1; off < 64; off <<= 1) {
            int x = __shfl_up(sc, (unsigned)off, 64);
            if (t >= off) sc += x;
        }
        if (t == b) sbase = sc - v;
        if (b == NB1 - 1 && t == NB1 - 1) rp[li * (Uu + 1) + Uu] = sc;  // == E
    }
    __syncthreads();
    for (int i = threadIdx.x; i < n; i += 256) atomicAdd(&hh[r[i] & 255], 1);
    __syncthreads();
    if (threadIdx.x < 64) {   // wave 0: 4x64 shfl scan with carry
        int carry = 0;
        #pragma unroll
        for (int c = 0; c < BW1 / 64; ++c) {
            int v = hh[c * 64 + (int)threadIdx.x];
            int sc = v;
            #pragma unroll
            for (int off = 1; off < 64; off <<= 1) {
                int x = __shfl_up(sc, (unsigned)off, 64);
                if ((int)threadIdx.x >= off) sc += x;
            }
            ofs[c * 64 + (int)threadIdx.x] = carry + sc - v;
            carry += __shfl(sc, 63, 64);
        }
    }
    __syncthreads();
    int base = sbase;
    if (threadIdx.x < BW1) {
        int dg = b * BW1 + (int)threadIdx.x;
        if (dg < Uu) rp[li * (Uu + 1) + dg] = base + ofs[threadIdx.x];
    }
    __syncthreads();   // rp reads of ofs complete before sort mutates ofs
    for (int i = threadIdx.x; i < n; i += 256) {
        unsigned int p = r[i];
        int pos = atomicAdd(&ofs[p & 255], 1);
        lout[pos] = (unsigned short)(p >> 8);
    }
    __syncthreads();
    unsigned int* o = ssrc + (size_t)li * Ee + base;
    const unsigned int* ro = rowof + (size_t)li * Nn;
    for (int i = threadIdx.x; i < n; i += 256) o[i] = ro[lout[i]];
}

// Persistent kernel: all 8 layers (dynamic chunk queues + grid barriers) + head.
__global__ __launch_bounds__(256, 4) void fused_layers(
        unsigned short* __restrict__ h, unsigned int* __restrict__ h8,
        const unsigned int* __restrict__ ssrc, const int* __restrict__ rp,
        const int* __restrict__ dstu, const float* __restrict__ lw,
        const float* __restrict__ bias, const int* __restrict__ roots,
        const float* __restrict__ W, const float* __restrict__ hb,
        float* __restrict__ out, int* __restrict__ bar, int* __restrict__ work) {
    __shared__ int sChunk;
    __shared__ float s0[256], s1[256];

    for (int li = 0; li < Ll; ++li) {
        const unsigned int* sl = ssrc + (size_t)li * Ee;
        const int* rpl = rp + (size_t)li * (Uu + 1);
        const float wv = lw[li];
        const uint4* hp = (const uint4*)h8;   // row = 8 uint4
        for (;;) {
            __syncthreads();
            if (threadIdx.x == 0) sChunk = atomicAdd(&work[li], 1);
            __syncthreads();
            int chunk = sChunk;
            if (chunk >= NCHK) break;
            int idx = chunk * 256 + (int)threadIdx.x;
            int u = idx >> 5;
            int lane5 = idx & 31;     // 32 lanes per u
            int sub = lane5 >> 3;     // edge substream 0..3
            int l8 = lane5 & 7;       // 16B chunk of the 128B row
            int beg = rpl[u], end = rpl[u + 1];
            float acc[16];
            #pragma unroll
            for (int j = 0; j < 16; ++j) acc[j] = 0.f;
            f32x2 p;
            int k = beg + sub;
            for (; k + 4 < end; k += 8) {
                unsigned s0v = sl[k], s1v = sl[k + 4];
                uint4 v0 = hp[(size_t)s0v * 8 + l8];
                uint4 v1 = hp[(size_t)s1v * 8 + l8];
                p = __builtin_amdgcn_cvt_pk_f32_fp8(v0.x, false); acc[0] += p.x;  acc[1] += p.y;
                p = __builtin_amdgcn_cvt_pk_f32_fp8(v0.x, true);  acc[2] += p.x;  acc[3] += p.y;
                p = __builtin_amdgcn_cvt_pk_f32_fp8(v0.y, false); acc[4] += p.x;  acc[5] += p.y;
                p = __builtin_amdgcn_cvt_pk_f32_fp8(v0.y, true);  acc[6] += p.x;  acc[7] += p.y;
                p = __builtin_amdgcn_cvt_pk_f32_fp8(v0.z, false); acc[8] += p.x;  acc[9] += p.y;
                p = __builtin_amdgcn_cvt_pk_f32_fp8(v0.z, true);  acc[10] += p.x; acc[11] += p.y;
                p = __builtin_amdgcn_cvt_pk_f32_fp8(v0.w, false); acc[12] += p.x; acc[13] += p.y;
                p = __builtin_amdgcn_cvt_pk_f32_fp8(v0.w, true);  acc[14] += p.x; acc[15] += p.y;
                p = __builtin_amdgcn_cvt_pk_f32_fp8(v1.x, false); acc[0] += p.x;  acc[1] += p.y;
                p = __builtin_amdgcn_cvt_pk_f32_fp8(v1.x, true);  acc[2] += p.x;  acc[3] += p.y;
                p = __builtin_amdgcn_cvt_pk_f32_fp8(v1.y, false); acc[4] += p.x;  acc[5] += p.y;
                p = __builtin_amdgcn_cvt_pk_f32_fp8(v1.y, true);  acc[6] += p.x;  acc[7] += p.y;
                p = __builtin_amdgcn_cvt_pk_f32_fp8(v1.z, false); acc[8] += p.x;  acc[9] += p.y;
                p = __builtin_amdgcn_cvt_pk_f32_fp8(v1.z, true);  acc[10] += p.x; acc[11] += p.y;
                p = __builtin_amdgcn_cvt_pk_f32_fp8(v1.w, false); acc[12] += p.x; acc[13] += p.y;
                p = __builtin_amdgcn_cvt_pk_f32_fp8(v1.w, true);  acc[14] += p.x; acc[15] += p.y;
            }
            if (k < end) {
                uint4 v0 = hp[(size_t)sl[k] * 8 + l8];
                p = __builtin_amdgcn_cvt_pk_f32_fp8(v0.x, false); acc[0] += p.x;  acc[1] += p.y;
                p = __builtin_amdgcn_cvt_pk_f32_fp8(v0.x, true);  acc[2] += p.x;  acc[3] += p.y;
                p = __builtin_amdgcn_cvt_pk_f32_fp8(v0.y, false); acc[4] += p.x;  acc[5] += p.y;
                p = __builtin_amdgcn_cvt_pk_f32_fp8(v0.y, true);  acc[6] += p.x;  acc[7] += p.y;
                p = __builtin_amdgcn_cvt_pk_f32_fp8(v0.z, false); acc[8] += p.x;  acc[9] += p.y;
                p = __builtin_amdgcn_cvt_pk_f32_fp8(v0.z, true);  acc[10] += p.x; acc[11] += p.y;
                p = __builtin_amdgcn_cvt_pk_f32_fp8(v0.w, false); acc[12] += p.x; acc[13] += p.y;
                p = __builtin_amdgcn_cvt_pk_f32_fp8(v0.w, true);  acc[14] += p.x; acc[15] += p.y;
            }
            #pragma unroll
            for (int j = 0; j < 16; ++j) {
                acc[j] += __shfl_xor(acc[j], 8, 64);
                acc[j] += __shfl_xor(acc[j], 16, 64);
            }
            if (sub == 0) {
                int node = dstu[li * Uu + u];
                float bs = bias[node];
                float t[16];
                #pragma unroll
                for (int j = 0; j < 16; ++j) t[j] = tanhf(acc[j] * wv + bs);
                uint4 o0, o1;
                o0.x = pkbf(t[0], t[1]);   o0.y = pkbf(t[2], t[3]);
                o0.z = pkbf(t[4], t[5]);   o0.w = pkbf(t[6], t[7]);
                o1.x = pkbf(t[8], t[9]);   o1.y = pkbf(t[10], t[11]);
                o1.z = pkbf(t[12], t[13]); o1.w = pkbf(t[14], t[15]);
                *(uint4*)(h + (size_t)node * Bb + l8 * 16) = o0;       // direct node write
                *(uint4*)(h + (size_t)node * Bb + l8 * 16 + 8) = o1;
                if (li < NSTG) {                                       // append-only fp8 log
                    uint4 of;
                    int w8;
                    w8 = __builtin_amdgcn_cvt_pk_fp8_f32(t[0], t[1], 0, false);
                    w8 = __builtin_amdgcn_cvt_pk_fp8_f32(t[2], t[3], w8, true);   of.x = (unsigned)w8;
                    w8 = __builtin_amdgcn_cvt_pk_fp8_f32(t[4], t[5], 0, false);
                    w8 = __builtin_amdgcn_cvt_pk_fp8_f32(t[6], t[7], w8, true);   of.y = (unsigned)w8;
                    w8 = __builtin_amdgcn_cvt_pk_fp8_f32(t[8], t[9], 0, false);
                    w8 = __builtin_amdgcn_cvt_pk_fp8_f32(t[10], t[11], w8, true); of.z = (unsigned)w8;
                    w8 = __builtin_amdgcn_cvt_pk_fp8_f32(t[12], t[13], 0, false);
                    w8 = __builtin_amdgcn_cvt_pk_fp8_f32(t[14], t[15], w8, true); of.w = (unsigned)w8;
                    *(uint4*)(h8 + (size_t)(Nn + li * Uu + u) * 32 + l8 * 4) = of;
                }
            }
        }
        // ---- grid barrier (release -> arrive -> spin -> acquire) ----
        __threadfence();
        __syncthreads();
        if (threadIdx.x == 0) {
            atomicAdd(&bar[li], 1);
            while (atomicCAS(&bar[li], GRID, GRID) < GRID) __builtin_amdgcn_s_sleep(8);
        }
        __syncthreads();
        __threadfence();
    }

    // ---- head (blocks 0..127, one batch row each) ----
    int b = blockIdx.x;
    if (b < Bb) {
        int t = threadIdx.x;
        float a0 = 0.f, a1 = 0.f;
        for (int r = t; r < Rr; r += 256) {
            float v = b2f(h[(size_t)roots[r] * Bb + b]);
            a0 += v * W[r];
            a1 += v * W[Rr + r];
        }
        s0[t] = a0; s1[t] = a1;
        __syncthreads();
        for (int off = 128; off > 0; off >>= 1) {
            if (t < off) { s0[t] += s0[t + off]; s1[t] += s1[t + off]; }
            __syncthreads();
        }
        if (t == 0) {
            out[b * Cc + 0] = s0[0] + hb[0];
            out[b * Cc + 1] = s1[0] + hb[1];
        }
    }
}

extern "C" void kernel_launch(void* const* d_in, const int* in_sizes, int n_in,
                              void* d_out, int out_size, void* d_ws, size_t ws_size,
                              hipStream_t stream) {
    const float* X      = (const float*)d_in[0];
    const float* lw     = (const float*)d_in[1];
    const float* bias   = (const float*)d_in[2];
    const float* headW  = (const float*)d_in[3];
    const float* headb  = (const float*)d_in[4];
    const int*   gmap   = (const int*)d_in[5];
    const int*   src    = (const int*)d_in[6];
    const int*   dstp   = (const int*)d_in[7];
    const int*   dstu   = (const int*)d_in[8];
    const int*   roots  = (const int*)d_in[9];
    float* out = (float*)d_out;

    char* w = (char*)d_ws;
    unsigned short* h_t    = (unsigned short*)w; w += (size_t)Nn * Bb * 2;               // 12.8 MB
    unsigned int*   h8     = (unsigned int*)w;   w += (size_t)(Nn + NSTG * Uu) * Bb;     // 15.36 MB
    unsigned int*   region = (unsigned int*)w;   w += (size_t)Ll * NB1 * CAP * 4;        // 9.5 MB
    unsigned int*   ssrc   = (unsigned int*)w;   w += (size_t)Ll * Ee * 4;               // 8 MB
    int*            rp     = (int*)w;            w += (size_t)Ll * (Uu + 1) * 4;         // 320 KB
    unsigned short* postab = (unsigned short*)w; w += (size_t)Ll * Nn * 2;               // 800 KB
    unsigned int*   rowof  = (unsigned int*)w;   w += (size_t)Ll * Nn * 4;               // 1.6 MB
    int*            gcur   = (int*)w;            w += (size_t)Ll * NB1 * 4;              // 1.3 KB
    int*            bar    = (int*)w;            w += (size_t)Ll * 4;                    // 32 B
    int*            work   = (int*)w;            w += (size_t)Ll * 4;                    // 32 B

    const int BLK = 256;

    zero_kernel<<<(Nn * 64 + BLK - 1) / BLK, BLK, 0, stream>>>(
        (unsigned int*)h_t, h8, (unsigned int*)postab, gcur, bar, work);
    genes_kernel<<<Gg / 32, BLK, 0, stream>>>(X, gmap, dstu, h_t, h8, postab);
    rowof_kernel<<<(Nn + BLK - 1) / BLK, BLK, 0, stream>>>(postab, rowof);

    // CSR build: two-pass scatter partition -> counting-sort emit (rowof remap)
    part_kernel<<<Ll * CH2, BLK, 0, stream>>>(src, dstp, gcur, region);
    emit_kernel<<<Ll * NB1, BLK, 0, stream>>>(region, gcur, rowof, ssrc, rp);

    // all 8 layers + head: one persistent dispatch
    fused_layers<<<GRID, BLK, 0, stream>>>(
        h_t, h8, ssrc, rp, dstu, lw, bias, roots, headW, headb, out, bar, work);
}

// Round 14
// 150.016 us; speedup vs baseline: 14.2791x; 14.2791x over previous
//
#include <hip/hip_runtime.h>

// Problem constants (from reference)
constexpr int Bb = 128;    // batch
constexpr int Nn = 50000;  // nodes
constexpr int Ll = 8;      // layers
constexpr int Ee = 250000; // edges per layer
constexpr int Uu = 10000;  // unique dst per layer
constexpr int Gg = 20000;  // genes
constexpr int Rr = 2000;   // roots
constexpr int Cc = 2;      // classes

// Binning parameters
constexpr int NB1 = 40;    // buckets (dst >> 8), 256 dsts each
constexpr int BW1 = 256;   // dsts per bucket
constexpr int CAP = 7424;  // region entries per (layer,bucket); mean 6400, sd ~79
constexpr int CH2 = 256;   // partition blocks per layer
constexpr int RIT = Uu * 32;  // reduce work items per layer
constexpr int NSTG = 7;    // fp8 staging slots (layer 7's outputs never re-read)

typedef __attribute__((ext_vector_type(2))) float f32x2;

// h_t (bf16, node rows only, 256B/row): written by genes + DIRECT node-row writes
//   from every reduce (no reader until head -> dispatch order = .at[].set order).
// h8 (fp8 e4m3, 128B/row): node rows [0,Nn) = initial values; append-only log
//   slots [Nn + li*Uu, +Uu) = layer li's outputs (li<7). The ONLY gather source.
// rowof[li][n] = row of n's latest value BEFORE layer li (precomputed, baked
//   into ssrc by emit) -> per-dispatch read/write row sets disjoint, no scatter.
// Round 14: layer inner loop unroll-4 (4 row-fetches in flight per lane).

__device__ __forceinline__ float b2f(unsigned short x) {
    return __uint_as_float((unsigned)x << 16);
}
__device__ __forceinline__ unsigned short f2b(float f) {  // RTNE
    unsigned u = __float_as_uint(f);
    return (unsigned short)((u + 0x7FFFu + ((u >> 16) & 1u)) >> 16);
}
__device__ __forceinline__ unsigned pkbf(float a, float b) {
    return (unsigned)f2b(a) | ((unsigned)f2b(b) << 16);
}

__global__ void zero_kernel(unsigned int* __restrict__ hz, unsigned int* __restrict__ h8z,
                            unsigned int* __restrict__ pz, int* __restrict__ gcur) {
    int idx = blockIdx.x * blockDim.x + threadIdx.x;
    if (idx < Nn * 64) hz[idx] = 0u;                 // h_t node rows (bf16)
    if (idx < Nn * 32) h8z[idx] = 0u;                // h8 node rows (fp8 0x00 == 0.0)
    if (idx < Ll * Nn / 2) pz[idx] = 0xFFFFFFFFu;    // postab init (0xFFFF per u16)
    if (idx < Ll * NB1) gcur[idx] = 0;
}

// gene scatter (LDS tile transpose) into BOTH mirrors + postab fill.
__global__ __launch_bounds__(256) void genes_kernel(const float* __restrict__ X,
                                                    const int* __restrict__ gmap,
                                                    const int* __restrict__ dstu,
                                                    unsigned short* __restrict__ h,
                                                    unsigned int* __restrict__ h8,
                                                    unsigned short* __restrict__ postab) {
    int gt = blockIdx.x * 256 + (int)threadIdx.x;
    if (gt < Ll * Uu) {
        int li = gt / Uu;
        postab[(size_t)li * Nn + dstu[gt]] = (unsigned short)(gt - li * Uu);
    }
    int g0 = blockIdx.x * 32;
    __shared__ float tile[32][129];
    #pragma unroll
    for (int i = 0; i < 16; ++i) {
        int idx = i * 256 + (int)threadIdx.x;
        int gl = idx & 31, b = idx >> 5;          // b in 0..127
        tile[gl][b] = X[(size_t)b * Gg + g0 + gl];
    }
    __syncthreads();
    #pragma unroll
    for (int i = 0; i < 16; ++i) {
        int idx = i * 256 + (int)threadIdx.x;
        int b = idx & 127, gl = idx >> 7;         // gl in 0..31
        h[(size_t)gmap[g0 + gl] * Bb + b] = f2b(tile[gl][b]);
    }
    #pragma unroll
    for (int i = 0; i < 4; ++i) {
        int idx = i * 256 + (int)threadIdx.x;     // 0..1023
        int q = idx & 31, gl = idx >> 5;          // q = b-quad, gl in 0..31
        int node = gmap[g0 + gl];
        int w8 = __builtin_amdgcn_cvt_pk_fp8_f32(tile[gl][q * 4 + 0], tile[gl][q * 4 + 1], 0, false);
        w8 = __builtin_amdgcn_cvt_pk_fp8_f32(tile[gl][q * 4 + 2], tile[gl][q * 4 + 3], w8, true);
        h8[(size_t)node * 32 + q] = (unsigned int)w8;
    }
}

// rowof[li][n]: row of n's latest value before layer li. Thread-per-node,
// sequential over layers within the thread (no cross-thread deps).
__global__ void rowof_kernel(const unsigned short* __restrict__ postab,
                             unsigned int* __restrict__ rowof) {
    int n = blockIdx.x * 256 + (int)threadIdx.x;
    if (n >= Nn) return;
    unsigned r = (unsigned)n;
    rowof[n] = r;                                 // level 0: identity
    #pragma unroll
    for (int li = 1; li < Ll; ++li) {
        unsigned short p = postab[(size_t)(li - 1) * Nn + n];
        if (p != 0xFFFFu) r = (unsigned)(Nn + (li - 1) * Uu + (int)p);
        rowof[(size_t)li * Nn + n] = r;
    }
}

// Two-pass direct scatter partition (unchanged).
__global__ __launch_bounds__(256) void part_kernel(const int* __restrict__ src,
                                                   const int* __restrict__ dstp,
                                                   int* __restrict__ gcur,
                                                   unsigned int* __restrict__ region) {
    int li = blockIdx.x / CH2, ch = blockIdx.x % CH2;
    const int ePer = (Ee + CH2 - 1) / CH2;        // 977
    int e0 = ch * ePer, e1 = min(e0 + ePer, Ee);
    const int* s = src + (size_t)li * Ee;
    const int* d = dstp + (size_t)li * Ee;

    __shared__ int hist[NB1];
    __shared__ int base[NB1];
    __shared__ int cur[NB1];
    if (threadIdx.x < NB1) { hist[threadIdx.x] = 0; cur[threadIdx.x] = 0; }
    __syncthreads();

    for (int e = e0 + (int)threadIdx.x; e < e1; e += 256)
        atomicAdd(&hist[d[e] >> 8], 1);
    __syncthreads();

    if (threadIdx.x < NB1) {
        int c = hist[threadIdx.x];
        base[threadIdx.x] = (c > 0) ? atomicAdd(&gcur[li * NB1 + (int)threadIdx.x], c) : 0;
    }
    __syncthreads();

    for (int e = e0 + (int)threadIdx.x; e < e1; e += 256) {
        int dd = d[e];
        int bkt = dd >> 8;
        unsigned int packed = ((unsigned int)s[e] << 8) | (unsigned int)(dd & 255);
        int pos = base[bkt] + atomicAdd(&cur[bkt], 1);
        region[((size_t)li * NB1 + bkt) * CAP + pos] = packed;
    }
}

// Per-bucket counting sort (256 bins) in LDS; writes rp + rowof-remapped ssrc.
__global__ __launch_bounds__(256) void emit_kernel(const unsigned int* __restrict__ region,
                                                   const int* __restrict__ gcur,
                                                   const unsigned int* __restrict__ rowof,
                                                   unsigned int* __restrict__ ssrc,
                                                   int* __restrict__ rp) {
    int li = blockIdx.x / NB1, b = blockIdx.x % NB1;
    int n = gcur[li * NB1 + b];
    const unsigned int* r = region + ((size_t)li * NB1 + b) * CAP;
    __shared__ int hh[BW1];
    __shared__ int ofs[BW1];
    __shared__ int sbase;
    __shared__ unsigned short lout[CAP];
    if (threadIdx.x < BW1) hh[threadIdx.x] = 0;
    // wave 0: inline exclusive prefix over the 40 bucket totals -> this bucket's base
    if (threadIdx.x < 64) {
        int t = threadIdx.x;
        int v = (t < NB1) ? gcur[li * NB1 + t] : 0;
        int sc = v;
        #pragma unroll
        for (int off = 1; off < 64; off <<= 1) {
            int x = __shfl_up(sc, (unsigned)off, 64);
            if (t >= off) sc += x;
        }
        if (t == b) sbase = sc - v;
        if (b == NB1 - 1 && t == NB1 - 1) rp[li * (Uu + 1) + Uu] = sc;  // == E
    }
    __syncthreads();
    for (int i = threadIdx.x; i < n; i += 256) atomicAdd(&hh[r[i] & 255], 1);
    __syncthreads();
    if (threadIdx.x < 64) {   // wave 0: 4x64 shfl scan with carry
        int carry = 0;
        #pragma unroll
        for (int c = 0; c < BW1 / 64; ++c) {
            int v = hh[c * 64 + (int)threadIdx.x];
            int sc = v;
            #pragma unroll
            for (int off = 1; off < 64; off <<= 1) {
                int x = __shfl_up(sc, (unsigned)off, 64);
                if ((int)threadIdx.x >= off) sc += x;
            }
            ofs[c * 64 + (int)threadIdx.x] = carry + sc - v;
            carry += __shfl(sc, 63, 64);
        }
    }
    __syncthreads();
    int base = sbase;
    if (threadIdx.x < BW1) {
        int dg = b * BW1 + (int)threadIdx.x;
        if (dg < Uu) rp[li * (Uu + 1) + dg] = base + ofs[threadIdx.x];
    }
    __syncthreads();   // rp reads of ofs complete before sort mutates ofs
    for (int i = threadIdx.x; i < n; i += 256) {
        unsigned int p = r[i];
        int pos = atomicAdd(&ofs[p & 255], 1);
        lout[pos] = (unsigned short)(p >> 8);
    }
    __syncthreads();
    unsigned int* o = ssrc + (size_t)li * Ee + base;
    const unsigned int* ro = rowof + (size_t)li * Nn;
    for (int i = threadIdx.x; i < n; i += 256) o[i] = ro[lout[i]];
}

#define ACC8(v)                                                                  \
    p = __builtin_amdgcn_cvt_pk_f32_fp8((v).x, false); acc[0] += p.x;  acc[1] += p.y;  \
    p = __builtin_amdgcn_cvt_pk_f32_fp8((v).x, true);  acc[2] += p.x;  acc[3] += p.y;  \
    p = __builtin_amdgcn_cvt_pk_f32_fp8((v).y, false); acc[4] += p.x;  acc[5] += p.y;  \
    p = __builtin_amdgcn_cvt_pk_f32_fp8((v).y, true);  acc[6] += p.x;  acc[7] += p.y;  \
    p = __builtin_amdgcn_cvt_pk_f32_fp8((v).z, false); acc[8] += p.x;  acc[9] += p.y;  \
    p = __builtin_amdgcn_cvt_pk_f32_fp8((v).z, true);  acc[10] += p.x; acc[11] += p.y; \
    p = __builtin_amdgcn_cvt_pk_f32_fp8((v).w, false); acc[12] += p.x; acc[13] += p.y; \
    p = __builtin_amdgcn_cvt_pk_f32_fp8((v).w, true);  acc[14] += p.x; acc[15] += p.y;

// Reduce-only layer: u = 32 lanes = 4 edge-substreams x 8 lanes; rows gathered
// as dwordx4 with 4 fetches in flight. bf16 -> node row; fp8 -> log slot li.
__global__ __launch_bounds__(256) void layer_kernel(unsigned short* __restrict__ h,
                                                    unsigned int* __restrict__ h8,
                                                    const unsigned int* __restrict__ ssrc,
                                                    const int* __restrict__ rp,
                                                    const int* __restrict__ dstu,
                                                    const float* __restrict__ lw,
                                                    const float* __restrict__ bias,
                                                    int li) {
    int idx = blockIdx.x * 256 + (int)threadIdx.x;
    if (idx >= RIT) return;
    int u = idx >> 5;
    int lane5 = idx & 31;     // 32 lanes per u
    int sub = lane5 >> 3;     // edge substream 0..3
    int l8 = lane5 & 7;       // 16B chunk of the 128B row
    int beg = rp[u], end = rp[u + 1];
    const uint4* hp = (const uint4*)h8;   // row = 8 uint4
    float acc[16];
    #pragma unroll
    for (int j = 0; j < 16; ++j) acc[j] = 0.f;
    f32x2 p;
    int k = beg + sub;
    // unroll 4: edges k, k+4, k+8, k+12 of this substream in flight together
    for (; k + 12 < end; k += 16) {
        unsigned s0 = ssrc[k], s1 = ssrc[k + 4], s2 = ssrc[k + 8], s3 = ssrc[k + 12];
        uint4 v0 = hp[(size_t)s0 * 8 + l8];
        uint4 v1 = hp[(size_t)s1 * 8 + l8];
        uint4 v2 = hp[(size_t)s2 * 8 + l8];
        uint4 v3 = hp[(size_t)s3 * 8 + l8];
        ACC8(v0); ACC8(v1); ACC8(v2); ACC8(v3);
    }
    // unroll 2 remainder
    for (; k + 4 < end; k += 8) {
        unsigned s0 = ssrc[k], s1 = ssrc[k + 4];
        uint4 v0 = hp[(size_t)s0 * 8 + l8];
        uint4 v1 = hp[(size_t)s1 * 8 + l8];
        ACC8(v0); ACC8(v1);
    }
    if (k < end) {
        uint4 v0 = hp[(size_t)ssrc[k] * 8 + l8];
        ACC8(v0);
    }
    // combine the 4 substreams (xor 8, 16 stay within the 32-lane u group)
    #pragma unroll
    for (int j = 0; j < 16; ++j) {
        acc[j] += __shfl_xor(acc[j], 8, 64);
        acc[j] += __shfl_xor(acc[j], 16, 64);
    }
    if (sub == 0) {
        float wv = lw[li];
        int node = dstu[li * Uu + u];
        float bs = bias[node];
        float t[16];
        #pragma unroll
        for (int j = 0; j < 16; ++j) t[j] = tanhf(acc[j] * wv + bs);
        uint4 o0, o1;
        o0.x = pkbf(t[0], t[1]);   o0.y = pkbf(t[2], t[3]);
        o0.z = pkbf(t[4], t[5]);   o0.w = pkbf(t[6], t[7]);
        o1.x = pkbf(t[8], t[9]);   o1.y = pkbf(t[10], t[11]);
        o1.z = pkbf(t[12], t[13]); o1.w = pkbf(t[14], t[15]);
        *(uint4*)(h + (size_t)node * Bb + l8 * 16) = o0;       // direct node write
        *(uint4*)(h + (size_t)node * Bb + l8 * 16 + 8) = o1;
        if (li < NSTG) {                                       // append-only fp8 log
            uint4 of;
            int w8;
            w8 = __builtin_amdgcn_cvt_pk_fp8_f32(t[0], t[1], 0, false);
            w8 = __builtin_amdgcn_cvt_pk_fp8_f32(t[2], t[3], w8, true);   of.x = (unsigned)w8;
            w8 = __builtin_amdgcn_cvt_pk_fp8_f32(t[4], t[5], 0, false);
            w8 = __builtin_amdgcn_cvt_pk_fp8_f32(t[6], t[7], w8, true);   of.y = (unsigned)w8;
            w8 = __builtin_amdgcn_cvt_pk_fp8_f32(t[8], t[9], 0, false);
            w8 = __builtin_amdgcn_cvt_pk_fp8_f32(t[10], t[11], w8, true); of.z = (unsigned)w8;
            w8 = __builtin_amdgcn_cvt_pk_fp8_f32(t[12], t[13], 0, false);
            w8 = __builtin_amdgcn_cvt_pk_fp8_f32(t[14], t[15], w8, true); of.w = (unsigned)w8;
            *(uint4*)(h8 + (size_t)(Nn + li * Uu + u) * 32 + l8 * 4) = of;
        }
    }
}

// Head: plain bf16 node-row reads (direct writes made node rows authoritative).
__global__ void head_kernel(const unsigned short* __restrict__ h,
                            const int* __restrict__ roots,
                            const float* __restrict__ W, const float* __restrict__ hb,
                            float* __restrict__ out) {
    int b = blockIdx.x;
    int t = threadIdx.x;
    float a0 = 0.f, a1 = 0.f;
    for (int r = t; r < Rr; r += 256) {
        float v = b2f(h[(size_t)roots[r] * Bb + b]);
        a0 += v * W[r];
        a1 += v * W[Rr + r];
    }
    __shared__ float s0[256], s1[256];
    s0[t] = a0; s1[t] = a1;
    __syncthreads();
    for (int off = 128; off > 0; off >>= 1) {
        if (t < off) { s0[t] += s0[t + off]; s1[t] += s1[t + off]; }
        __syncthreads();
    }
    if (t == 0) {
        out[b * Cc + 0] = s0[0] + hb[0];
        out[b * Cc + 1] = s1[0] + hb[1];
    }
}

extern "C" void kernel_launch(void* const* d_in, const int* in_sizes, int n_in,
                              void* d_out, int out_size, void* d_ws, size_t ws_size,
                              hipStream_t stream) {
    const float* X      = (const float*)d_in[0];
    const float* lw     = (const float*)d_in[1];
    const float* bias   = (const float*)d_in[2];
    const float* headW  = (const float*)d_in[3];
    const float* headb  = (const float*)d_in[4];
    const int*   gmap   = (const int*)d_in[5];
    const int*   src    = (const int*)d_in[6];
    const int*   dstp   = (const int*)d_in[7];
    const int*   dstu   = (const int*)d_in[8];
    const int*   roots  = (const int*)d_in[9];
    float* out = (float*)d_out;

    char* w = (char*)d_ws;
    unsigned short* h_t    = (unsigned short*)w; w += (size_t)Nn * Bb * 2;               // 12.8 MB
    unsigned int*   h8     = (unsigned int*)w;   w += (size_t)(Nn + NSTG * Uu) * Bb;     // 15.36 MB
    unsigned int*   region = (unsigned int*)w;   w += (size_t)Ll * NB1 * CAP * 4;        // 9.5 MB
    unsigned int*   ssrc   = (unsigned int*)w;   w += (size_t)Ll * Ee * 4;               // 8 MB
    int*            rp     = (int*)w;            w += (size_t)Ll * (Uu + 1) * 4;         // 320 KB
    unsigned short* postab = (unsigned short*)w; w += (size_t)Ll * Nn * 2;               // 800 KB
    unsigned int*   rowof  = (unsigned int*)w;   w += (size_t)Ll * Nn * 4;               // 1.6 MB
    int*            gcur   = (int*)w;            w += (size_t)Ll * NB1 * 4;              // 1.3 KB

    const int BLK = 256;

    zero_kernel<<<(Nn * 64 + BLK - 1) / BLK, BLK, 0, stream>>>(
        (unsigned int*)h_t, h8, (unsigned int*)postab, gcur);
    genes_kernel<<<Gg / 32, BLK, 0, stream>>>(X, gmap, dstu, h_t, h8, postab);
    rowof_kernel<<<(Nn + BLK - 1) / BLK, BLK, 0, stream>>>(postab, rowof);

    // CSR build: two-pass scatter partition -> counting-sort emit (rowof remap)
    part_kernel<<<Ll * CH2, BLK, 0, stream>>>(src, dstp, gcur, region);
    emit_kernel<<<Ll * NB1, BLK, 0, stream>>>(region, gcur, rowof, ssrc, rp);

    // layers: reduce only (no scatter; fp8 log + direct bf16 node writes)
    for (int li = 0; li < Ll; ++li) {
        layer_kernel<<<(RIT + BLK - 1) / BLK, BLK, 0, stream>>>(
            h_t, h8, ssrc + (size_t)li * Ee, rp + (size_t)li * (Uu + 1),
            dstu, lw, bias, li);
    }

    head_kernel<<<Bb, 256, 0, stream>>>(h_t, roots, headW, headb, out);
}

// Round 15
// 135.781 us; speedup vs baseline: 15.7761x; 1.1048x over previous
//
#include <hip/hip_runtime.h>

// Problem constants (from reference)
constexpr int Bb = 128;    // batch
constexpr int Nn = 50000;  // nodes
constexpr int Ll = 8;      // layers
constexpr int Ee = 250000; // edges per layer
constexpr int Uu = 10000;  // unique dst per layer
constexpr int Gg = 20000;  // genes
constexpr int Rr = 2000;   // roots
constexpr int Cc = 2;      // classes

// Binning parameters
constexpr int NB1 = 40;    // buckets (dst >> 8), 256 dsts each
constexpr int BW1 = 256;   // dsts per bucket
constexpr int CAP = 7424;  // region entries per (layer,bucket); mean 6400, sd ~79
constexpr int CH2 = 256;   // partition blocks per layer
constexpr int RIT = Uu * 32;  // reduce work items per layer
constexpr int NSTG = 7;    // fp8 staging slots (layer 7's outputs never re-read)
constexpr int GB  = Gg / 32;  // 625 gene blocks in the merged genes+part dispatch

typedef __attribute__((ext_vector_type(2))) float f32x2;

// h_t (bf16, node rows, 256B/row): read ONLY by head at root rows -> zero only
//   root rows; layers write it only for root nodes (rbit map).
// h8 (fp8 e4m3, 128B/row): node rows [0,Nn) + append-only log slots
//   [Nn + li*Uu, +Uu) for layer li outputs (li<7). The ONLY gather source.
// rowof[li][n] = row of n's latest value BEFORE layer li (baked into ssrc by
//   emit) -> per-dispatch read/write row sets disjoint, no scatter copies.

__device__ __forceinline__ float b2f(unsigned short x) {
    return __uint_as_float((unsigned)x << 16);
}
__device__ __forceinline__ unsigned short f2b(float f) {  // RTNE
    unsigned u = __float_as_uint(f);
    return (unsigned short)((u + 0x7FFFu + ((u >> 16) & 1u)) >> 16);
}
__device__ __forceinline__ unsigned pkbf(float a, float b) {
    return (unsigned)f2b(a) | ((unsigned)f2b(b) << 16);
}

__global__ void zero_kernel(unsigned int* __restrict__ hz, unsigned int* __restrict__ h8z,
                            unsigned int* __restrict__ pz, int* __restrict__ gcur,
                            unsigned char* __restrict__ rbit, const int* __restrict__ roots) {
    int idx = blockIdx.x * blockDim.x + threadIdx.x;
    if (idx < Nn * 32) h8z[idx] = 0u;                // h8 node rows (fp8 0x00 == 0.0)
    if (idx < Ll * Nn / 2) pz[idx] = 0xFFFFFFFFu;    // postab init (0xFFFF per u16)
    if (idx < Rr * 64) {                             // zero only ROOT rows of h_t
        int r = idx >> 6, wv = idx & 63;
        hz[(size_t)roots[r] * 64 + wv] = 0u;
    }
    if (idx < Nn) rbit[idx] = 0;                     // root byte-map
    if (idx < Ll * NB1) gcur[idx] = 0;
}

// Merged dispatch: blocks [0,GB) = gene scatter (both mirrors) + postab + rbit;
// blocks [GB, GB+Ll*CH2) = two-pass edge partition. Fully independent work.
__global__ __launch_bounds__(256) void genes_part_kernel(
        const float* __restrict__ X, const int* __restrict__ gmap,
        const int* __restrict__ dstu, const int* __restrict__ roots,
        unsigned short* __restrict__ h, unsigned int* __restrict__ h8,
        unsigned short* __restrict__ postab, unsigned char* __restrict__ rbit,
        const int* __restrict__ src, const int* __restrict__ dstp,
        int* __restrict__ gcur, unsigned int* __restrict__ region) {
    __shared__ float tile[32][129];   // genes path (16.5 KB; part path uses a slice)
    if (blockIdx.x < GB) {
        int gt = blockIdx.x * 256 + (int)threadIdx.x;
        if (gt < Ll * Uu) {
            int li = gt / Uu;
            postab[(size_t)li * Nn + dstu[gt]] = (unsigned short)(gt - li * Uu);
        }
        if (gt < Rr) rbit[roots[gt]] = 1;
        int g0 = blockIdx.x * 32;
        #pragma unroll
        for (int i = 0; i < 16; ++i) {
            int idx = i * 256 + (int)threadIdx.x;
            int gl = idx & 31, b = idx >> 5;          // b in 0..127
            tile[gl][b] = X[(size_t)b * Gg + g0 + gl];
        }
        __syncthreads();
        #pragma unroll
        for (int i = 0; i < 16; ++i) {
            int idx = i * 256 + (int)threadIdx.x;
            int b = idx & 127, gl = idx >> 7;         // gl in 0..31
            h[(size_t)gmap[g0 + gl] * Bb + b] = f2b(tile[gl][b]);
        }
        #pragma unroll
        for (int i = 0; i < 4; ++i) {
            int idx = i * 256 + (int)threadIdx.x;     // 0..1023
            int q = idx & 31, gl = idx >> 5;          // q = b-quad, gl in 0..31
            int node = gmap[g0 + gl];
            int w8 = __builtin_amdgcn_cvt_pk_fp8_f32(tile[gl][q * 4 + 0], tile[gl][q * 4 + 1], 0, false);
            w8 = __builtin_amdgcn_cvt_pk_fp8_f32(tile[gl][q * 4 + 2], tile[gl][q * 4 + 3], w8, true);
            h8[(size_t)node * 32 + q] = (unsigned int)w8;
        }
    } else {
        int pb = blockIdx.x - GB;
        int li = pb / CH2, ch = pb % CH2;
        const int ePer = (Ee + CH2 - 1) / CH2;        // 977
        int e0 = ch * ePer, e1 = min(e0 + ePer, Ee);
        const int* s = src + (size_t)li * Ee;
        const int* d = dstp + (size_t)li * Ee;
        int* hist = (int*)&tile[0][0];
        int* base = hist + NB1;
        int* cur  = base + NB1;
        if (threadIdx.x < NB1) { hist[threadIdx.x] = 0; cur[threadIdx.x] = 0; }
        __syncthreads();
        for (int e = e0 + (int)threadIdx.x; e < e1; e += 256)
            atomicAdd(&hist[d[e] >> 8], 1);
        __syncthreads();
        if (threadIdx.x < NB1) {
            int c = hist[threadIdx.x];
            base[threadIdx.x] = (c > 0) ? atomicAdd(&gcur[li * NB1 + (int)threadIdx.x], c) : 0;
        }
        __syncthreads();
        for (int e = e0 + (int)threadIdx.x; e < e1; e += 256) {
            int dd = d[e];
            int bkt = dd >> 8;
            unsigned int packed = ((unsigned int)s[e] << 8) | (unsigned int)(dd & 255);
            int pos = base[bkt] + atomicAdd(&cur[bkt], 1);
            region[((size_t)li * NB1 + bkt) * CAP + pos] = packed;
        }
    }
}

// rowof[li][n]: row of n's latest value before layer li.
__global__ void rowof_kernel(const unsigned short* __restrict__ postab,
                             unsigned int* __restrict__ rowof) {
    int n = blockIdx.x * 256 + (int)threadIdx.x;
    if (n >= Nn) return;
    unsigned r = (unsigned)n;
    rowof[n] = r;                                 // level 0: identity
    #pragma unroll
    for (int li = 1; li < Ll; ++li) {
        unsigned short p = postab[(size_t)(li - 1) * Nn + n];
        if (p != 0xFFFFu) r = (unsigned)(Nn + (li - 1) * Uu + (int)p);
        rowof[(size_t)li * Nn + n] = r;
    }
}

// Per-bucket counting sort (256 bins) in LDS; writes rp + rowof-remapped ssrc.
__global__ __launch_bounds__(256) void emit_kernel(const unsigned int* __restrict__ region,
                                                   const int* __restrict__ gcur,
                                                   const unsigned int* __restrict__ rowof,
                                                   unsigned int* __restrict__ ssrc,
                                                   int* __restrict__ rp) {
    int li = blockIdx.x / NB1, b = blockIdx.x % NB1;
    int n = gcur[li * NB1 + b];
    const unsigned int* r = region + ((size_t)li * NB1 + b) * CAP;
    __shared__ int hh[BW1];
    __shared__ int ofs[BW1];
    __shared__ int sbase;
    __shared__ unsigned short lout[CAP];
    if (threadIdx.x < BW1) hh[threadIdx.x] = 0;
    // wave 0: inline exclusive prefix over the 40 bucket totals -> this bucket's base
    if (threadIdx.x < 64) {
        int t = threadIdx.x;
        int v = (t < NB1) ? gcur[li * NB1 + t] : 0;
        int sc = v;
        #pragma unroll
        for (int off = 1; off < 64; off <<= 1) {
            int x = __shfl_up(sc, (unsigned)off, 64);
            if (t >= off) sc += x;
        }
        if (t == b) sbase = sc - v;
        if (b == NB1 - 1 && t == NB1 - 1) rp[li * (Uu + 1) + Uu] = sc;  // == E
    }
    __syncthreads();
    for (int i = threadIdx.x; i < n; i += 256) atomicAdd(&hh[r[i] & 255], 1);
    __syncthreads();
    if (threadIdx.x < 64) {   // wave 0: 4x64 shfl scan with carry
        int carry = 0;
        #pragma unroll
        for (int c = 0; c < BW1 / 64; ++c) {
            int v = hh[c * 64 + (int)threadIdx.x];
            int sc = v;
            #pragma unroll
            for (int off = 1; off < 64; off <<= 1) {
                int x = __shfl_up(sc, (unsigned)off, 64);
                if ((int)threadIdx.x >= off) sc += x;
            }
            ofs[c * 64 + (int)threadIdx.x] = carry + sc - v;
            carry += __shfl(sc, 63, 64);
        }
    }
    __syncthreads();
    int base = sbase;
    if (threadIdx.x < BW1) {
        int dg = b * BW1 + (int)threadIdx.x;
        if (dg < Uu) rp[li * (Uu + 1) + dg] = base + ofs[threadIdx.x];
    }
    __syncthreads();   // rp reads of ofs complete before sort mutates ofs
    for (int i = threadIdx.x; i < n; i += 256) {
        unsigned int p = r[i];
        int pos = atomicAdd(&ofs[p & 255], 1);
        lout[pos] = (unsigned short)(p >> 8);
    }
    __syncthreads();
    unsigned int* o = ssrc + (size_t)li * Ee + base;
    const unsigned int* ro = rowof + (size_t)li * Nn;
    for (int i = threadIdx.x; i < n; i += 256) o[i] = ro[lout[i]];
}

// Reduce-only layer (round-12 unroll-2 loop): u = 32 lanes = 4 substreams x 8
// lanes; rows gathered as dwordx4. bf16 -> node row ONLY IF ROOT; fp8 -> log.
__global__ __launch_bounds__(256) void layer_kernel(unsigned short* __restrict__ h,
                                                    unsigned int* __restrict__ h8,
                                                    const unsigned int* __restrict__ ssrc,
                                                    const int* __restrict__ rp,
                                                    const int* __restrict__ dstu,
                                                    const float* __restrict__ lw,
                                                    const float* __restrict__ bias,
                                                    const unsigned char* __restrict__ rbit,
                                                    int li) {
    int idx = blockIdx.x * 256 + (int)threadIdx.x;
    if (idx >= RIT) return;
    int u = idx >> 5;
    int lane5 = idx & 31;     // 32 lanes per u
    int sub = lane5 >> 3;     // edge substream 0..3
    int l8 = lane5 & 7;       // 16B chunk of the 128B row
    int beg = rp[u], end = rp[u + 1];
    const uint4* hp = (const uint4*)h8;   // row = 8 uint4
    float acc[16];
    #pragma unroll
    for (int j = 0; j < 16; ++j) acc[j] = 0.f;
    f32x2 p;
    int k = beg + sub;
    // unroll 2: edges k, k+4 of this substream in flight together
    for (; k + 4 < end; k += 8) {
        unsigned s0 = ssrc[k], s1 = ssrc[k + 4];
        uint4 v0 = hp[(size_t)s0 * 8 + l8];
        uint4 v1 = hp[(size_t)s1 * 8 + l8];
        p = __builtin_amdgcn_cvt_pk_f32_fp8(v0.x, false); acc[0] += p.x;  acc[1] += p.y;
        p = __builtin_amdgcn_cvt_pk_f32_fp8(v0.x, true);  acc[2] += p.x;  acc[3] += p.y;
        p = __builtin_amdgcn_cvt_pk_f32_fp8(v0.y, false); acc[4] += p.x;  acc[5] += p.y;
        p = __builtin_amdgcn_cvt_pk_f32_fp8(v0.y, true);  acc[6] += p.x;  acc[7] += p.y;
        p = __builtin_amdgcn_cvt_pk_f32_fp8(v0.z, false); acc[8] += p.x;  acc[9] += p.y;
        p = __builtin_amdgcn_cvt_pk_f32_fp8(v0.z, true);  acc[10] += p.x; acc[11] += p.y;
        p = __builtin_amdgcn_cvt_pk_f32_fp8(v0.w, false); acc[12] += p.x; acc[13] += p.y;
        p = __builtin_amdgcn_cvt_pk_f32_fp8(v0.w, true);  acc[14] += p.x; acc[15] += p.y;
        p = __builtin_amdgcn_cvt_pk_f32_fp8(v1.x, false); acc[0] += p.x;  acc[1] += p.y;
        p = __builtin_amdgcn_cvt_pk_f32_fp8(v1.x, true);  acc[2] += p.x;  acc[3] += p.y;
        p = __builtin_amdgcn_cvt_pk_f32_fp8(v1.y, false); acc[4] += p.x;  acc[5] += p.y;
        p = __builtin_amdgcn_cvt_pk_f32_fp8(v1.y, true);  acc[6] += p.x;  acc[7] += p.y;
        p = __builtin_amdgcn_cvt_pk_f32_fp8(v1.z, false); acc[8] += p.x;  acc[9] += p.y;
        p = __builtin_amdgcn_cvt_pk_f32_fp8(v1.z, true);  acc[10] += p.x; acc[11] += p.y;
        p = __builtin_amdgcn_cvt_pk_f32_fp8(v1.w, false); acc[12] += p.x; acc[13] += p.y;
        p = __builtin_amdgcn_cvt_pk_f32_fp8(v1.w, true);  acc[14] += p.x; acc[15] += p.y;
    }
    if (k < end) {
        uint4 v0 = hp[(size_t)ssrc[k] * 8 + l8];
        p = __builtin_amdgcn_cvt_pk_f32_fp8(v0.x, false); acc[0] += p.x;  acc[1] += p.y;
        p = __builtin_amdgcn_cvt_pk_f32_fp8(v0.x, true);  acc[2] += p.x;  acc[3] += p.y;
        p = __builtin_amdgcn_cvt_pk_f32_fp8(v0.y, false); acc[4] += p.x;  acc[5] += p.y;
        p = __builtin_amdgcn_cvt_pk_f32_fp8(v0.y, true);  acc[6] += p.x;  acc[7] += p.y;
        p = __builtin_amdgcn_cvt_pk_f32_fp8(v0.z, false); acc[8] += p.x;  acc[9] += p.y;
        p = __builtin_amdgcn_cvt_pk_f32_fp8(v0.z, true);  acc[10] += p.x; acc[11] += p.y;
        p = __builtin_amdgcn_cvt_pk_f32_fp8(v0.w, false); acc[12] += p.x; acc[13] += p.y;
        p = __builtin_amdgcn_cvt_pk_f32_fp8(v0.w, true);  acc[14] += p.x; acc[15] += p.y;
    }
    // combine the 4 substreams (xor 8, 16 stay within the 32-lane u group)
    #pragma unroll
    for (int j = 0; j < 16; ++j) {
        acc[j] += __shfl_xor(acc[j], 8, 64);
        acc[j] += __shfl_xor(acc[j], 16, 64);
    }
    if (sub == 0) {
        float wv = lw[li];
        int node = dstu[li * Uu + u];
        float bs = bias[node];
        float t[16];
        #pragma unroll
        for (int j = 0; j < 16; ++j) t[j] = tanhf(acc[j] * wv + bs);
        if (rbit[node]) {   // h_t is only read at root rows -> skip other writes
            uint4 o0, o1;
            o0.x = pkbf(t[0], t[1]);   o0.y = pkbf(t[2], t[3]);
            o0.z = pkbf(t[4], t[5]);   o0.w = pkbf(t[6], t[7]);
            o1.x = pkbf(t[8], t[9]);   o1.y = pkbf(t[10], t[11]);
            o1.z = pkbf(t[12], t[13]); o1.w = pkbf(t[14], t[15]);
            *(uint4*)(h + (size_t)node * Bb + l8 * 16) = o0;
            *(uint4*)(h + (size_t)node * Bb + l8 * 16 + 8) = o1;
        }
        if (li < NSTG) {                                       // append-only fp8 log
            uint4 of;
            int w8;
            w8 = __builtin_amdgcn_cvt_pk_fp8_f32(t[0], t[1], 0, false);
            w8 = __builtin_amdgcn_cvt_pk_fp8_f32(t[2], t[3], w8, true);   of.x = (unsigned)w8;
            w8 = __builtin_amdgcn_cvt_pk_fp8_f32(t[4], t[5], 0, false);
            w8 = __builtin_amdgcn_cvt_pk_fp8_f32(t[6], t[7], w8, true);   of.y = (unsigned)w8;
            w8 = __builtin_amdgcn_cvt_pk_fp8_f32(t[8], t[9], 0, false);
            w8 = __builtin_amdgcn_cvt_pk_fp8_f32(t[10], t[11], w8, true); of.z = (unsigned)w8;
            w8 = __builtin_amdgcn_cvt_pk_fp8_f32(t[12], t[13], 0, false);
            w8 = __builtin_amdgcn_cvt_pk_fp8_f32(t[14], t[15], w8, true); of.w = (unsigned)w8;
            *(uint4*)(h8 + (size_t)(Nn + li * Uu + u) * 32 + l8 * 4) = of;
        }
    }
}

// Head: plain bf16 node-row reads (root rows are authoritative by construction).
__global__ void head_kernel(const unsigned short* __restrict__ h,
                            const int* __restrict__ roots,
                            const float* __restrict__ W, const float* __restrict__ hb,
                            float* __restrict__ out) {
    int b = blockIdx.x;
    int t = threadIdx.x;
    float a0 = 0.f, a1 = 0.f;
    for (int r = t; r < Rr; r += 256) {
        float v = b2f(h[(size_t)roots[r] * Bb + b]);
        a0 += v * W[r];
        a1 += v * W[Rr + r];
    }
    __shared__ float s0[256], s1[256];
    s0[t] = a0; s1[t] = a1;
    __syncthreads();
    for (int off = 128; off > 0; off >>= 1) {
        if (t < off) { s0[t] += s0[t + off]; s1[t] += s1[t + off]; }
        __syncthreads();
    }
    if (t == 0) {
        out[b * Cc + 0] = s0[0] + hb[0];
        out[b * Cc + 1] = s1[0] + hb[1];
    }
}

extern "C" void kernel_launch(void* const* d_in, const int* in_sizes, int n_in,
                              void* d_out, int out_size, void* d_ws, size_t ws_size,
                              hipStream_t stream) {
    const float* X      = (const float*)d_in[0];
    const float* lw     = (const float*)d_in[1];
    const float* bias   = (const float*)d_in[2];
    const float* headW  = (const float*)d_in[3];
    const float* headb  = (const float*)d_in[4];
    const int*   gmap   = (const int*)d_in[5];
    const int*   src    = (const int*)d_in[6];
    const int*   dstp   = (const int*)d_in[7];
    const int*   dstu   = (const int*)d_in[8];
    const int*   roots  = (const int*)d_in[9];
    float* out = (float*)d_out;

    char* w = (char*)d_ws;
    unsigned short* h_t    = (unsigned short*)w; w += (size_t)Nn * Bb * 2;               // 12.8 MB
    unsigned int*   h8     = (unsigned int*)w;   w += (size_t)(Nn + NSTG * Uu) * Bb;     // 15.36 MB
    unsigned int*   region = (unsigned int*)w;   w += (size_t)Ll * NB1 * CAP * 4;        // 9.5 MB
    unsigned int*   ssrc   = (unsigned int*)w;   w += (size_t)Ll * Ee * 4;               // 8 MB
    int*            rp     = (int*)w;            w += (size_t)Ll * (Uu + 1) * 4;         // 320 KB
    unsigned short* postab = (unsigned short*)w; w += (size_t)Ll * Nn * 2;               // 800 KB
    unsigned int*   rowof  = (unsigned int*)w;   w += (size_t)Ll * Nn * 4;               // 1.6 MB
    int*            gcur   = (int*)w;            w += (size_t)Ll * NB1 * 4;              // 1.3 KB
    unsigned char*  rbit   = (unsigned char*)w;  w += (size_t)((Nn + 63) & ~63);         // 50 KB

    const int BLK = 256;

    zero_kernel<<<(Nn * 32 + BLK - 1) / BLK, BLK, 0, stream>>>(
        (unsigned int*)h_t, h8, (unsigned int*)postab, gcur, rbit, roots);

    // merged: gene scatter + edge partition (independent work, one dispatch)
    genes_part_kernel<<<GB + Ll * CH2, BLK, 0, stream>>>(
        X, gmap, dstu, roots, h_t, h8, postab, rbit, src, dstp, gcur, region);

    rowof_kernel<<<(Nn + BLK - 1) / BLK, BLK, 0, stream>>>(postab, rowof);
    emit_kernel<<<Ll * NB1, BLK, 0, stream>>>(region, gcur, rowof, ssrc, rp);

    // layers: reduce only (no scatter; fp8 log + root-only bf16 node writes)
    for (int li = 0; li < Ll; ++li) {
        layer_kernel<<<(RIT + BLK - 1) / BLK, BLK, 0, stream>>>(
            h_t, h8, ssrc + (size_t)li * Ee, rp + (size_t)li * (Uu + 1),
            dstu, lw, bias, rbit, li);
    }

    head_kernel<<<Bb, 256, 0, stream>>>(h_t, roots, headW, headb, out);
}